// Round 19
// baseline (785.619 us; speedup 1.0000x reference)
//
#include <hip/hip_runtime.h>
#include <math.h>

#define NN 64
#define CC 160
#define LL 4096
#define DD 160
#define MM 6
#define NCH 16      // chunks per image; chunk = 256 tokens = 4 tiles of 64
#define NT 4
#define XSTR 68     // xb row stride in tokens (136B: b64 conflict-free)

#if defined(__has_builtin)
#if __has_builtin(__builtin_amdgcn_fdot2_f32_bf16)
#define HAVE_DOT2 1
#endif
#endif

__device__ __forceinline__ unsigned short f2bf(float f) {
  union { float f; unsigned int i; } v; v.f = f;
  unsigned int r = v.i + 0x7fffu + ((v.i >> 16) & 1u);
  return (unsigned short)(r >> 16);
}
__device__ __forceinline__ float u2f_lo(unsigned int w) {
  union { unsigned int i; float f; } v; v.i = w << 16; return v.f;
}
__device__ __forceinline__ float u2f_hi(unsigned int w) {
  union { unsigned int i; float f; } v; v.i = w & 0xffff0000u; return v.f;
}

#if HAVE_DOT2
typedef __bf16 v2bf __attribute__((ext_vector_type(2)));
__device__ __forceinline__ float dot2bf(unsigned int a, unsigned int b, float c) {
  union { unsigned int u; v2bf v; } ua, ub;
  ua.u = a; ub.u = b;
  return __builtin_amdgcn_fdot2_f32_bf16(ua.v, ub.v, c, false);
}
#else
__device__ __forceinline__ float dot2bf(unsigned int a, unsigned int b, float c) {
  return fmaf(u2f_hi(a), u2f_hi(b), fmaf(u2f_lo(a), u2f_lo(b), c));
}
#endif

// ================= k_init (fixed): 512 thr, wave-parallel stats, group dots =================
__device__ __forceinline__ void init_body(
    const float* log_tau, const float* slots_init, const float* q_g, const float* q_b,
    const float* Wq, const float* Wk, float* Wkq1, float* scal,
    float* ln, float* qv, float* mu_s, float* rs_s, int bi, int tid) {
  float x = log_tau[0];
  float sp = (x > 20.f) ? x : log1pf(expf(x));
  float scv = (1.0f / sqrtf((float)DD)) / (sp + 0.5f);
  if (bi == 0 && tid == 0) scal[0] = scv;
  int w = tid >> 6, l = tid & 63;
  if (w < MM) {
    float x0 = slots_init[w * DD + l];
    float x1 = slots_init[w * DD + l + 64];
    float x2 = (l < 32) ? slots_init[w * DD + l + 128] : 0.f;
    float s = x0 + x1 + x2, ss = x0 * x0 + x1 * x1 + x2 * x2;
#pragma unroll
    for (int off = 32; off >= 1; off >>= 1) { s += __shfl_xor(s, off); ss += __shfl_xor(ss, off); }
    if (l == 0) {
      float mu = s / DD, var = ss / DD - mu * mu;
      mu_s[w] = mu; rs_s[w] = rsqrtf(var + 1e-5f);
    }
  }
  __syncthreads();
  for (int o = tid; o < MM * DD; o += 512) {
    int m = o / DD, d = o % DD;
    ln[o] = (slots_init[o] - mu_s[m]) * rs_s[m] * q_g[d] + q_b[d];
  }
  __syncthreads();
  for (int o = tid; o < MM * DD; o += 512) {
    int m = o / DD, d = o % DD;
    float acc = 0.f;
#pragma unroll 8
    for (int i = 0; i < DD; i++) acc = fmaf(ln[m * DD + i], Wq[i * DD + d], acc);
    qv[o] = acc;
  }
  __syncthreads();
  // Wkq1 rows [bi*10, bi*10+10): 60 tasks over 32 groups of 16 lanes
  int grp = tid >> 4, l4 = tid & 15;
#pragma unroll
  for (int t = grp; t < 60; t += 32) {
    int c = bi * 10 + t / 6, m = t % 6;
    float s = 0.f;
#pragma unroll
    for (int i = 0; i < 10; i++) {
      int d = l4 + i * 16;
      s = fmaf(Wk[c * DD + d], qv[m * DD + d], s);
    }
    s += __shfl_xor(s, 1); s += __shfl_xor(s, 2);
    s += __shfl_xor(s, 4); s += __shfl_xor(s, 8);
    if (l4 == 0) Wkq1[c * 6 + m] = scv * s;
  }
}

__global__ __launch_bounds__(512) void k_init(
    const float* log_tau, const float* slots_init, const float* q_g, const float* q_b,
    const float* Wq, const float* Wk, float* Wkq1, float* scal) {
  __shared__ float ln[MM * DD];
  __shared__ float qv[MM * DD];
  __shared__ float mu_s[MM], rs_s[MM];
  init_body(log_tau, slots_init, q_g, q_b, Wq, Wk, Wkq1, scal,
            ln, qv, mu_s, rs_s, blockIdx.x, threadIdx.x);
}

__global__ __launch_bounds__(512) void k_initP(
    const float* log_tau, const float* slots_init, const float* q_g, const float* q_b,
    const float* Wq, const float* Wk, float* Wkq1S, float* scalS) {
  __shared__ float ln[MM * DD];
  __shared__ float qv[MM * DD];
  __shared__ float mu_s[MM], rs_s[MM];
#pragma unroll 1
  for (int rep = 0; rep < 16; rep++) {
    init_body(log_tau, slots_init, q_g, q_b, Wq, Wk, Wkq1S, scalS,
              ln, qv, mu_s, rs_s, blockIdx.x, threadIdx.x);
    __syncthreads();
  }
}

// ================= k_init2 =================
__device__ __forceinline__ void init2_body(
    const float* Wkq1, const float* kv_g, const float* kv_b, float* P1, float* ab, int tid) {
  for (int o = tid; o < DD * 6; o += 256) {
    int c = o / 6;
    P1[o] = kv_g[c] * Wkq1[o];
  }
  if (tid < 192) {
    int grp = tid >> 4;
    int l = tid & 15;
    int m = grp % 6;
    const float* coef = (grp < 6) ? kv_g : kv_b;
    float s = 0.f;
#pragma unroll
    for (int i = 0; i < 10; i++) {
      int c = l + i * 16;
      s += coef[c] * Wkq1[c * 6 + m];
    }
    s += __shfl_xor(s, 1); s += __shfl_xor(s, 2);
    s += __shfl_xor(s, 4); s += __shfl_xor(s, 8);
    if (l == 0) ab[grp] = s;
  }
}

__global__ __launch_bounds__(256) void k_init2(
    const float* Wkq1, const float* kv_g, const float* kv_b, float* P1, float* ab) {
  init2_body(Wkq1, kv_g, kv_b, P1, ab, threadIdx.x);
}

__global__ __launch_bounds__(256) void k_init2P(
    const float* Wkq1, const float* kv_g, const float* kv_b, float* P1S, float* abS) {
#pragma unroll 1
  for (int rep = 0; rep < 32; rep++) {
    init2_body(Wkq1, kv_g, kv_b, P1S, abS, threadIdx.x);
    __syncthreads();
  }
}

// ================= tile body (shared by k_pass) =================
struct TileShared {
  unsigned short xb[160 * XSTR];
  float part[4][16][4][10];
  unsigned int w2_s[32][8];
  float P_s[160][8];
};

template <bool ITER2>
__device__ __forceinline__ void tile_body(
    TileShared* sh, const float* __restrict__ fb, const float* alpha, const float* beta,
    int tid, int lane, int g, int cg, int tl,
    float* Aacc, float* Sacc,
    float* __restrict__ attn_out, size_t attn_base) {
  float s4[4] = {0, 0, 0, 0}, ss4[4] = {0, 0, 0, 0};
  float lgr[6][4];
#pragma unroll
  for (int m = 0; m < 6; m++) { lgr[m][0] = 0.f; lgr[m][1] = 0.f; lgr[m][2] = 0.f; lgr[m][3] = 0.f; }
#pragma unroll
  for (int r = 0; r < 10; r++) {
    int c = g * 40 + r * 4 + cg;
    float4 xv = *(const float4*)(fb + (size_t)(r * 4) * LL);
    float4 p03 = *(const float4*)&sh->P_s[c][0];
    float2 p45 = *(const float2*)&sh->P_s[c][4];
    float xs[4] = {xv.x, xv.y, xv.z, xv.w};
#pragma unroll
    for (int j = 0; j < 4; j++) {
      float x = xs[j];
      s4[j] += x; ss4[j] = fmaf(x, x, ss4[j]);
      lgr[0][j] = fmaf(x, p03.x, lgr[0][j]); lgr[1][j] = fmaf(x, p03.y, lgr[1][j]);
      lgr[2][j] = fmaf(x, p03.z, lgr[2][j]); lgr[3][j] = fmaf(x, p03.w, lgr[3][j]);
      lgr[4][j] = fmaf(x, p45.x, lgr[4][j]); lgr[5][j] = fmaf(x, p45.y, lgr[5][j]);
    }
    uint2 pk;
    pk.x = (unsigned int)f2bf(xv.x) | ((unsigned int)f2bf(xv.y) << 16);
    pk.y = (unsigned int)f2bf(xv.z) | ((unsigned int)f2bf(xv.w) << 16);
    *(uint2*)&sh->xb[c * XSTR + 4 * tl] = pk;
  }
#pragma unroll
  for (int j = 0; j < 4; j++) {
    s4[j] += __shfl_xor(s4[j], 16);  s4[j] += __shfl_xor(s4[j], 32);
    ss4[j] += __shfl_xor(ss4[j], 16); ss4[j] += __shfl_xor(ss4[j], 32);
#pragma unroll
    for (int m = 0; m < 6; m++) {
      lgr[m][j] += __shfl_xor(lgr[m][j], 16);
      lgr[m][j] += __shfl_xor(lgr[m][j], 32);
    }
  }
  if (cg == 0) {
#pragma unroll
    for (int j = 0; j < 4; j++) {
      float* pp = &sh->part[g][tl][j][0];
      *(float2*)&pp[0] = make_float2(s4[j], ss4[j]);
      *(float2*)&pp[2] = make_float2(lgr[0][j], lgr[1][j]);
      *(float2*)&pp[4] = make_float2(lgr[2][j], lgr[3][j]);
      *(float2*)&pp[6] = make_float2(lgr[4][j], lgr[5][j]);
    }
  }
  __syncthreads();
  {
    int tg = lane >> 2, tj = lane & 3;
    float S = 0.f, SS = 0.f, L[6] = {0, 0, 0, 0, 0, 0};
#pragma unroll
    for (int g2 = 0; g2 < 4; g2++) {
      const float* pp = &sh->part[g2][tg][tj][0];
      float2 a = *(const float2*)&pp[0];
      float2 b2_ = *(const float2*)&pp[2];
      float2 c2 = *(const float2*)&pp[4];
      float2 d2 = *(const float2*)&pp[6];
      S += a.x; SS += a.y;
      L[0] += b2_.x; L[1] += b2_.y; L[2] += c2.x; L[3] += c2.y; L[4] += d2.x; L[5] += d2.y;
    }
    float mu = S * (1.0f / CC);
    float var = SS * (1.0f / CC) - mu * mu;
    float rs = rsqrtf(var + 1e-5f);
    float lg[6];
#pragma unroll
    for (int m = 0; m < 6; m++) lg[m] = rs * L[m] - rs * mu * alpha[m] + beta[m];
    float mx = lg[0];
#pragma unroll
    for (int m = 1; m < 6; m++) mx = fmaxf(mx, lg[m]);
    float e[6], sum = 0.f;
#pragma unroll
    for (int m = 0; m < 6; m++) { e[m] = __expf(lg[m] - mx); sum += e[m]; }
    float inv = 1.0f / sum;
    float att[6], wv[6];
#pragma unroll
    for (int m = 0; m < 6; m++) { att[m] = e[m] * inv; wv[m] = att[m] * rs; }
    if (g == 0) {
      float wo[6];
#pragma unroll
      for (int m = 0; m < 6; m++) wo[m] = __shfl_xor(wv[m], 1);
      if (!(lane & 1)) {
        int tp = lane >> 1;
        unsigned int pk[6];
#pragma unroll
        for (int m = 0; m < 6; m++) pk[m] = (unsigned int)f2bf(wv[m]) | ((unsigned int)f2bf(wo[m]) << 16);
        *(uint4*)&sh->w2_s[tp][0] = make_uint4(pk[0], pk[1], pk[2], pk[3]);
        *(uint2*)&sh->w2_s[tp][4] = make_uint2(pk[4], pk[5]);
      }
    } else if (g == 1) {
      if (ITER2) {
#pragma unroll
        for (int m = 0; m < 6; m++) attn_out[attn_base + lane + (size_t)m * LL] = att[m];
      }
    } else if (g == 2) {
#pragma unroll
      for (int m = 0; m < 6; m++) Sacc[m] += att[m];
    } else {
#pragma unroll
      for (int m = 0; m < 6; m++) Sacc[m] += wv[m] * mu;
    }
  }
  __syncthreads();
  if (tid < DD) {
    const unsigned short* xr = &sh->xb[tid * XSTR];
#pragma unroll
    for (int k = 0; k < 16; k++) {
      uint2 xw = *(const uint2*)(xr + 4 * k);
      uint4 wa0 = *(const uint4*)&sh->w2_s[2 * k][0];
      uint2 wb0 = *(const uint2*)&sh->w2_s[2 * k][4];
      uint4 wa1 = *(const uint4*)&sh->w2_s[2 * k + 1][0];
      uint2 wb1 = *(const uint2*)&sh->w2_s[2 * k + 1][4];
      Aacc[0] = dot2bf(wa0.x, xw.x, Aacc[0]); Aacc[1] = dot2bf(wa0.y, xw.x, Aacc[1]);
      Aacc[2] = dot2bf(wa0.z, xw.x, Aacc[2]); Aacc[3] = dot2bf(wa0.w, xw.x, Aacc[3]);
      Aacc[4] = dot2bf(wb0.x, xw.x, Aacc[4]); Aacc[5] = dot2bf(wb0.y, xw.x, Aacc[5]);
      Aacc[0] = dot2bf(wa1.x, xw.y, Aacc[0]); Aacc[1] = dot2bf(wa1.y, xw.y, Aacc[1]);
      Aacc[2] = dot2bf(wa1.z, xw.y, Aacc[2]); Aacc[3] = dot2bf(wa1.w, xw.y, Aacc[3]);
      Aacc[4] = dot2bf(wb1.x, xw.y, Aacc[4]); Aacc[5] = dot2bf(wb1.y, xw.y, Aacc[5]);
    }
  }
  __syncthreads();
}

// ================= k_pass: 4 tiles/block, grid 1024 =================
template <bool ITER2>
__global__ __launch_bounds__(256) void k_pass(
    const float* __restrict__ feat, const float* __restrict__ Pg,
    const float* __restrict__ abg, float* __restrict__ Apart,
    float* __restrict__ SWpart, float* __restrict__ attn_out) {
  int b = blockIdx.x;
  int n = b >> 4, ch = b & 15;
  int tid = threadIdx.x;
  int lane = tid & 63, g = tid >> 6;
  int cg = lane >> 4, tl = lane & 15;
  __shared__ TileShared sh;

  const float* wsrc = ITER2 ? (Pg + (size_t)n * DD * 6) : Pg;
  for (int o = tid; o < DD * 6; o += 256) sh.P_s[o / 6][o % 6] = wsrc[o];
  const float* absrc = ITER2 ? (abg + n * 12) : abg;
  float alpha[6], beta[6];
#pragma unroll
  for (int m = 0; m < 6; m++) { alpha[m] = absrc[m]; beta[m] = absrc[6 + m]; }
  float Aacc[6] = {0, 0, 0, 0, 0, 0};
  float Sacc[6] = {0, 0, 0, 0, 0, 0};
  __syncthreads();

  const float* fb0 = feat + ((size_t)(n * CC + g * 40 + cg)) * LL + ch * (64 * NT) + 4 * tl;
#pragma unroll 1
  for (int t4 = 0; t4 < NT; t4++) {
    size_t ab_ = ((size_t)(n * MM)) * LL + ch * (64 * NT) + t4 * 64;
    tile_body<ITER2>(&sh, fb0 + t4 * 64, alpha, beta, tid, lane, g, cg, tl, Aacc, Sacc, attn_out, ab_);
  }
  if (g == 2 || g == 3) {
#pragma unroll
    for (int m = 0; m < 6; m++) {
      float v = Sacc[m];
      v += __shfl_xor(v, 1);  v += __shfl_xor(v, 2);  v += __shfl_xor(v, 4);
      v += __shfl_xor(v, 8);  v += __shfl_xor(v, 16); v += __shfl_xor(v, 32);
      if (lane == 0) SWpart[b * 12 + (g - 2) * 6 + m] = v;
    }
  }
  if (tid < DD) {
#pragma unroll
    for (int m = 0; m < 6; m++) Apart[((size_t)b * 6 + m) * DD + tid] = Aacc[m];
  }
}

// ================= k_slot3 (body shared with probe) =================
template <bool FIRST, bool LAST>
__device__ __forceinline__ void slot3_body(
    const float* __restrict__ slots_init, const float* __restrict__ Apart,
    const float* __restrict__ SWpart, const float* __restrict__ Wv,
    const float* __restrict__ out_g, const float* __restrict__ out_b,
    const float* __restrict__ W1, const float* __restrict__ b1,
    const float* __restrict__ W2, const float* __restrict__ b2,
    const float* __restrict__ q_g, const float* __restrict__ q_b,
    const float* __restrict__ Wq, const float* __restrict__ Wk,
    const float* __restrict__ kv_g, const float* __restrict__ kv_b,
    const float* __restrict__ scal,
    float* __restrict__ slotbuf, float* __restrict__ P2, float* __restrict__ ab2,
    float* __restrict__ Sfin, float* __restrict__ out_slots,
    float* a_s, float* s1, float* h, float* pg, float* pb,
    float* sw_s, float* Sv_s, float* mu_s, float* rs_s,
    int n, int m, int tid) {
  if (tid < 32) {
    int p = tid & 15, which = tid >> 4;
    float v = SWpart[(size_t)(n * NCH + p) * 12 + m + 6 * which];
    v += __shfl_xor(v, 1); v += __shfl_xor(v, 2);
    v += __shfl_xor(v, 4); v += __shfl_xor(v, 8);
    if (p == 0) {
      sw_s[which] = v;
      if (which == 0) {
        float sc = fmaxf(v, 1e-6f);
        *Sv_s = sc;
        if (LAST) Sfin[n * 6 + m] = sc;
      }
    }
  }
  __syncthreads();
  if (tid < DD) {
    const float* src = Apart + ((size_t)(n * NCH) * 6 + m) * DD + tid;
    float ar = 0.f;
#pragma unroll
    for (int p = 0; p < NCH; p++) ar += src[(size_t)p * 6 * DD];
    a_s[tid] = kv_g[tid] * (ar - sw_s[1]) + kv_b[tid] * sw_s[0];
  }
  __syncthreads();
  if (tid < DD) {
    float u = 0.f;
#pragma unroll 8
    for (int c = 0; c < DD; c++) u = fmaf(a_s[c], Wv[c * DD + tid], u);
    float prev = FIRST ? slots_init[m * DD + tid] : slotbuf[(size_t)n * MM * DD + m * DD + tid];
    s1[tid] = prev + u / (*Sv_s);
  }
  __syncthreads();
  if (tid < 64) {
    float x0 = s1[tid], x1 = s1[tid + 64], x2 = (tid < 32) ? s1[tid + 128] : 0.f;
    float s = x0 + x1 + x2, ss = x0 * x0 + x1 * x1 + x2 * x2;
#pragma unroll
    for (int off = 32; off >= 1; off >>= 1) { s += __shfl_xor(s, off); ss += __shfl_xor(ss, off); }
    if (tid == 0) {
      float mu = s / DD, var = ss / DD - mu * mu;
      *mu_s = mu; *rs_s = rsqrtf(var + 1e-5f);
    }
  }
  __syncthreads();
  if (tid < DD) s1[tid] = (s1[tid] - *mu_s) * (*rs_s) * out_g[tid] + out_b[tid];
  __syncthreads();
  for (int j = tid; j < 320; j += 256) {
    float acc = b1[j];
#pragma unroll 8
    for (int d = 0; d < DD; d++) acc = fmaf(s1[d], W1[d * 320 + j], acc);
    h[j] = 0.5f * acc * (1.0f + erff(acc * 0.70710678118f));
  }
  __syncthreads();
  if (tid < DD) {
    float acc = b2[tid];
#pragma unroll 8
    for (int j = 0; j < 320; j++) acc = fmaf(h[j], W2[j * DD + tid], acc);
    float val = s1[tid] + acc;
    a_s[tid] = val;
    if (LAST) out_slots[(size_t)n * MM * DD + m * DD + tid] = val;
    else slotbuf[(size_t)n * MM * DD + m * DD + tid] = val;
  }
  if (!LAST) {
    __syncthreads();
    if (tid < 64) {
      float x0 = a_s[tid], x1 = a_s[tid + 64], x2 = (tid < 32) ? a_s[tid + 128] : 0.f;
      float s = x0 + x1 + x2, ss = x0 * x0 + x1 * x1 + x2 * x2;
#pragma unroll
      for (int off = 32; off >= 1; off >>= 1) { s += __shfl_xor(s, off); ss += __shfl_xor(ss, off); }
      if (tid == 0) {
        float mu = s / DD, var = ss / DD - mu * mu;
        *mu_s = mu; *rs_s = rsqrtf(var + 1e-5f);
      }
    }
    __syncthreads();
    if (tid < DD) s1[tid] = (a_s[tid] - *mu_s) * (*rs_s) * q_g[tid] + q_b[tid];
    __syncthreads();
    if (tid < DD) {
      float acc = 0.f;
#pragma unroll 8
      for (int i = 0; i < DD; i++) acc = fmaf(s1[i], Wq[i * DD + tid], acc);
      h[tid] = acc;
    }
    __syncthreads();
    {
      int grp = tid >> 4, l = tid & 15;
      float sc = scal[0];
#pragma unroll 2
      for (int p = 0; p < 10; p++) {
        int c = p * 16 + grp;
        float s = 0.f;
#pragma unroll
        for (int i = 0; i < 10; i++) {
          int d = l + i * 16;
          s = fmaf(Wk[c * DD + d], h[d], s);
        }
        s += __shfl_xor(s, 1); s += __shfl_xor(s, 2);
        s += __shfl_xor(s, 4); s += __shfl_xor(s, 8);
        if (l == 0) {
          float wr = sc * s;
          float gv = kv_g[c] * wr;
          P2[(size_t)n * DD * 6 + c * 6 + m] = gv;
          pg[c] = gv;
          pb[c] = kv_b[c] * wr;
        }
      }
    }
    __syncthreads();
    if (tid < 128) {
      int w = tid >> 6, l = tid & 63;
      const float* src = (w == 0) ? pg : pb;
      float x0 = src[l], x1 = src[l + 64], x2 = (l < 32) ? src[l + 128] : 0.f;
      float s = x0 + x1 + x2;
#pragma unroll
      for (int off = 32; off >= 1; off >>= 1) s += __shfl_xor(s, off);
      if (l == 0) ab2[n * 12 + 6 * w + m] = s;
    }
  }
}

template <bool FIRST, bool LAST>
__global__ __launch_bounds__(256) void k_slot3(
    const float* __restrict__ slots_init, const float* __restrict__ Apart,
    const float* __restrict__ SWpart, const float* __restrict__ Wv,
    const float* __restrict__ out_g, const float* __restrict__ out_b,
    const float* __restrict__ W1, const float* __restrict__ b1,
    const float* __restrict__ W2, const float* __restrict__ b2,
    const float* __restrict__ q_g, const float* __restrict__ q_b,
    const float* __restrict__ Wq, const float* __restrict__ Wk,
    const float* __restrict__ kv_g, const float* __restrict__ kv_b,
    const float* __restrict__ scal,
    float* __restrict__ slotbuf, float* __restrict__ P2, float* __restrict__ ab2,
    float* __restrict__ Sfin, float* __restrict__ out_slots) {
  __shared__ float a_s[DD], s1[DD], h[320], pg[DD], pb[DD];
  __shared__ float sw_s[2], Sv_s, mu_s, rs_s;
  int b = blockIdx.x;
  slot3_body<FIRST, LAST>(slots_init, Apart, SWpart, Wv, out_g, out_b, W1, b1, W2, b2,
                          q_g, q_b, Wq, Wk, kv_g, kv_b, scal, slotbuf, P2, ab2, Sfin, out_slots,
                          a_s, s1, h, pg, pb, sw_s, &Sv_s, &mu_s, &rs_s,
                          b / MM, b % MM, threadIdx.x);
}

__global__ __launch_bounds__(256) void k_slot3P(
    const float* __restrict__ slots_init, const float* __restrict__ Apart,
    const float* __restrict__ SWpart, const float* __restrict__ Wv,
    const float* __restrict__ out_g, const float* __restrict__ out_b,
    const float* __restrict__ W1, const float* __restrict__ b1,
    const float* __restrict__ W2, const float* __restrict__ b2,
    const float* __restrict__ q_g, const float* __restrict__ q_b,
    const float* __restrict__ Wq, const float* __restrict__ Wk,
    const float* __restrict__ kv_g, const float* __restrict__ kv_b,
    const float* __restrict__ scal,
    float* __restrict__ slotbufS, float* __restrict__ P2S, float* __restrict__ ab2S,
    float* __restrict__ SfinS, float* __restrict__ outS) {
  __shared__ float a_s[DD], s1[DD], h[320], pg[DD], pb[DD];
  __shared__ float sw_s[2], Sv_s, mu_s, rs_s;
  int b = blockIdx.x;
#pragma unroll 1
  for (int rep = 0; rep < 16; rep++) {
    slot3_body<true, false>(slots_init, Apart, SWpart, Wv, out_g, out_b, W1, b1, W2, b2,
                            q_g, q_b, Wq, Wk, kv_g, kv_b, scal, slotbufS, P2S, ab2S, SfinS, outS,
                            a_s, s1, h, pg, pb, sw_s, &Sv_s, &mu_s, &rs_s,
                            b / MM, b % MM, threadIdx.x);
    __syncthreads();
  }
}

// ================= k_norm =================
__global__ __launch_bounds__(256) void k_norm(float* attn, const float* Sfin) {
  int idx = blockIdx.x * 256 + threadIdx.x;
  size_t base = (size_t)idx * 4;
  int nm = (int)(base >> 12);
  float s = Sfin[nm];
  float4 v = *(float4*)(attn + base);
  float inv = 1.0f / s;
  v.x *= inv; v.y *= inv; v.z *= inv; v.w *= inv;
  *(float4*)(attn + base) = v;
}

extern "C" void kernel_launch(void* const* d_in, const int* in_sizes, int n_in,
                              void* d_out, int out_size, void* d_ws, size_t ws_size,
                              hipStream_t stream) {
  const float* feat       = (const float*)d_in[0];
  const float* slots_init = (const float*)d_in[1];
  const float* log_tau    = (const float*)d_in[2];
  const float* kv_g       = (const float*)d_in[3];
  const float* kv_b       = (const float*)d_in[4];
  const float* Wk         = (const float*)d_in[5];
  const float* Wv         = (const float*)d_in[6];
  const float* q_g        = (const float*)d_in[7];
  const float* q_b        = (const float*)d_in[8];
  const float* Wq         = (const float*)d_in[9];
  const float* out_g      = (const float*)d_in[10];
  const float* out_b      = (const float*)d_in[11];
  const float* W1         = (const float*)d_in[12];
  const float* b1         = (const float*)d_in[13];
  const float* W2         = (const float*)d_in[14];
  const float* b2         = (const float*)d_in[15];
  float* out = (float*)d_out;
  float* out_attn = out + NN * MM * DD;

  float* Wkq1   = (float*)d_ws;                          // [160*6]
  float* ab     = Wkq1 + DD * 6;                         // [12] (pad 16)
  float* P1     = ab + 16;                               // [160*6]
  float* P2     = P1 + DD * 6;                           // [64][160*6]
  float* ab2    = P2 + (size_t)NN * DD * 6;              // [64][12]
  float* Apart  = ab2 + NN * 12;                         // [1024][6][160]
  float* SWpart = Apart + (size_t)NN * NCH * MM * DD;    // [1024][12]
  float* Sfin   = SWpart + (size_t)NN * NCH * 12;        // [64][6]
  float* scal   = Sfin + NN * MM;                        // [1] (pad 8)
  float* slotbuf = scal + 8;                             // [64][6][160]
  float* endbase = slotbuf + NN * MM * DD;
  size_t required = (size_t)((char*)endbase - (char*)d_ws);
  if (ws_size < required) return;

  k_init<<<16, 512, 0, stream>>>(log_tau, slots_init, q_g, q_b, Wq, Wk, Wkq1, scal);
  k_init2<<<1, 256, 0, stream>>>(Wkq1, kv_g, kv_b, P1, ab);
  k_pass<false><<<NN * NCH, 256, 0, stream>>>(feat, P1, ab, Apart, SWpart, out_attn);
  k_slot3<true, false><<<NN * MM, 256, 0, stream>>>(slots_init, Apart, SWpart, Wv, out_g, out_b,
                                                    W1, b1, W2, b2, q_g, q_b, Wq, Wk, kv_g, kv_b, scal,
                                                    slotbuf, P2, ab2, Sfin, out);
  k_pass<true><<<NN * NCH, 256, 0, stream>>>(feat, P2, ab2, Apart, SWpart, out_attn);
  k_slot3<false, true><<<NN * MM, 256, 0, stream>>>(slots_init, Apart, SWpart, Wv, out_g, out_b,
                                                    W1, b1, W2, b2, q_g, q_b, Wq, Wk, kv_g, kv_b, scal,
                                                    slotbuf, P2, ab2, Sfin, out);
  k_norm<<<(NN * MM * LL) / 1024, 256, 0, stream>>>(out_attn, Sfin);

  // ---- probes: rep-looped clones of the small kernels, writing to scratch ----
  float* Wkq1S   = endbase;                      // [976]
  float* scalS   = Wkq1S + DD * 6 + 16;          // [8]
  float* P1S     = scalS + 8;                    // [960+16]
  float* abS     = P1S + DD * 6 + 16;            // [16]
  float* slotbufS = abS + 16;                    // [64*6*160]
  float* P2S     = slotbufS + NN * MM * DD;      // [64*960]
  float* ab2S    = P2S + (size_t)NN * DD * 6;    // [64*12]
  float* SfinS   = ab2S + NN * 12;               // [384]
  float* outS    = SfinS + NN * MM;              // [64*6*160] (unused: LAST=false)
  size_t req_probe = (size_t)((char*)(outS + NN * MM * DD) - (char*)d_ws);
  if (ws_size >= req_probe) {
    k_initP<<<16, 512, 0, stream>>>(log_tau, slots_init, q_g, q_b, Wq, Wk, Wkq1S, scalS);
    k_init2P<<<1, 256, 0, stream>>>(Wkq1, kv_g, kv_b, P1S, abS);
    k_slot3P<<<NN * MM, 256, 0, stream>>>(slots_init, Apart, SWpart, Wv, out_g, out_b,
                                          W1, b1, W2, b2, q_g, q_b, Wq, Wk, kv_g, kv_b, scal,
                                          slotbufS, P2S, ab2S, SfinS, outS);
  }
}

// Round 20
// 210.145 us; speedup vs baseline: 3.7385x; 3.7385x over previous
//
#include <hip/hip_runtime.h>
#include <math.h>

#define NN 64
#define CC 160
#define LL 4096
#define DD 160
#define MM 6
#define NCH 16      // chunks per image; chunk = 256 tokens = 4 tiles of 64
#define NT 4
#define XSTR 68     // xb row stride in tokens (136B: b64 conflict-free)

#if defined(__has_builtin)
#if __has_builtin(__builtin_amdgcn_fdot2_f32_bf16)
#define HAVE_DOT2 1
#endif
#endif

__device__ __forceinline__ unsigned short f2bf(float f) {
  union { float f; unsigned int i; } v; v.f = f;
  unsigned int r = v.i + 0x7fffu + ((v.i >> 16) & 1u);
  return (unsigned short)(r >> 16);
}
__device__ __forceinline__ float u2f_lo(unsigned int w) {
  union { unsigned int i; float f; } v; v.i = w << 16; return v.f;
}
__device__ __forceinline__ float u2f_hi(unsigned int w) {
  union { unsigned int i; float f; } v; v.i = w & 0xffff0000u; return v.f;
}

#if HAVE_DOT2
typedef __bf16 v2bf __attribute__((ext_vector_type(2)));
__device__ __forceinline__ float dot2bf(unsigned int a, unsigned int b, float c) {
  union { unsigned int u; v2bf v; } ua, ub;
  ua.u = a; ub.u = b;
  return __builtin_amdgcn_fdot2_f32_bf16(ua.v, ub.v, c, false);
}
#else
__device__ __forceinline__ float dot2bf(unsigned int a, unsigned int b, float c) {
  return fmaf(u2f_hi(a), u2f_hi(b), fmaf(u2f_lo(a), u2f_lo(b), c));
}
#endif

// ================= k_trans: one-time weight transposes (WvT, WqT, W1T, W2T) =================
__global__ __launch_bounds__(256) void k_trans(
    const float* __restrict__ Wv, const float* __restrict__ Wq,
    const float* __restrict__ W1, const float* __restrict__ W2,
    float* __restrict__ WvT, float* __restrict__ WqT,
    float* __restrict__ W1T, float* __restrict__ W2T) {
  int b = blockIdx.x;
  const float* src; float* dst; int R, C, tr, tc;
  if (b < 25)       { src = Wv; dst = WvT; R = 160; C = 160; int t = b;       tr = t / 5;  tc = t % 5; }
  else if (b < 50)  { src = Wq; dst = WqT; R = 160; C = 160; int t = b - 25;  tr = t / 5;  tc = t % 5; }
  else if (b < 100) { src = W1; dst = W1T; R = 160; C = 320; int t = b - 50;  tr = t / 10; tc = t % 10; }
  else              { src = W2; dst = W2T; R = 320; C = 160; int t = b - 100; tr = t / 5;  tc = t % 5; }
  __shared__ float tile[32][33];
  int r0 = tr * 32, c0 = tc * 32;
  int lr = threadIdx.x >> 5, lc = threadIdx.x & 31;
#pragma unroll
  for (int i = 0; i < 4; i++)
    tile[lr + i * 8][lc] = src[(size_t)(r0 + lr + i * 8) * C + c0 + lc];
  __syncthreads();
#pragma unroll
  for (int i = 0; i < 4; i++)
    dst[(size_t)(c0 + lr + i * 8) * R + r0 + lc] = tile[lc][lr + i * 8];
}

// ================= k_init: 512 thr, wave-parallel stats, group dots =================
__global__ __launch_bounds__(512) void k_init(
    const float* log_tau, const float* slots_init, const float* q_g, const float* q_b,
    const float* Wq, const float* Wk, float* Wkq1, float* scal) {
  __shared__ float ln[MM * DD];
  __shared__ float qv[MM * DD];
  __shared__ float mu_s[MM], rs_s[MM];
  int bi = blockIdx.x, tid = threadIdx.x;
  float x = log_tau[0];
  float sp = (x > 20.f) ? x : log1pf(expf(x));
  float scv = (1.0f / sqrtf((float)DD)) / (sp + 0.5f);
  if (bi == 0 && tid == 0) scal[0] = scv;
  int w = tid >> 6, l = tid & 63;
  if (w < MM) {
    float x0 = slots_init[w * DD + l];
    float x1 = slots_init[w * DD + l + 64];
    float x2 = (l < 32) ? slots_init[w * DD + l + 128] : 0.f;
    float s = x0 + x1 + x2, ss = x0 * x0 + x1 * x1 + x2 * x2;
#pragma unroll
    for (int off = 32; off >= 1; off >>= 1) { s += __shfl_xor(s, off); ss += __shfl_xor(ss, off); }
    if (l == 0) {
      float mu = s / DD, var = ss / DD - mu * mu;
      mu_s[w] = mu; rs_s[w] = rsqrtf(var + 1e-5f);
    }
  }
  __syncthreads();
  for (int o = tid; o < MM * DD; o += 512) {
    int m = o / DD, d = o % DD;
    ln[o] = (slots_init[o] - mu_s[m]) * rs_s[m] * q_g[d] + q_b[d];
  }
  __syncthreads();
  for (int o = tid; o < MM * DD; o += 512) {
    int m = o / DD, d = o % DD;
    float acc = 0.f;
#pragma unroll 8
    for (int i = 0; i < DD; i++) acc = fmaf(ln[m * DD + i], Wq[i * DD + d], acc);
    qv[o] = acc;
  }
  __syncthreads();
  int grp = tid >> 4, l4 = tid & 15;
#pragma unroll
  for (int t = grp; t < 60; t += 32) {
    int c = bi * 10 + t / 6, m = t % 6;
    float s = 0.f;
#pragma unroll
    for (int i = 0; i < 10; i++) {
      int d = l4 + i * 16;
      s = fmaf(Wk[c * DD + d], qv[m * DD + d], s);
    }
    s += __shfl_xor(s, 1); s += __shfl_xor(s, 2);
    s += __shfl_xor(s, 4); s += __shfl_xor(s, 8);
    if (l4 == 0) Wkq1[c * 6 + m] = scv * s;
  }
}

// ================= k_init2 =================
__global__ __launch_bounds__(256) void k_init2(
    const float* Wkq1, const float* kv_g, const float* kv_b, float* P1, float* ab) {
  int tid = threadIdx.x;
  for (int o = tid; o < DD * 6; o += 256) {
    int c = o / 6;
    P1[o] = kv_g[c] * Wkq1[o];
  }
  if (tid < 192) {
    int grp = tid >> 4;
    int l = tid & 15;
    int m = grp % 6;
    const float* coef = (grp < 6) ? kv_g : kv_b;
    float s = 0.f;
#pragma unroll
    for (int i = 0; i < 10; i++) {
      int c = l + i * 16;
      s += coef[c] * Wkq1[c * 6 + m];
    }
    s += __shfl_xor(s, 1); s += __shfl_xor(s, 2);
    s += __shfl_xor(s, 4); s += __shfl_xor(s, 8);
    if (l == 0) ab[grp] = s;
  }
}

// ================= tile body =================
struct TileShared {
  unsigned short xb[160 * XSTR];
  float part[4][16][4][10];
  unsigned int w2_s[32][8];
  float P_s[160][8];
};

template <bool ITER2>
__device__ __forceinline__ void tile_body(
    TileShared* sh, const float* __restrict__ fb, const float* alpha, const float* beta,
    int tid, int lane, int g, int cg, int tl,
    float* Aacc, float* Sacc,
    float* __restrict__ attn_out, size_t attn_base) {
  float s4[4] = {0, 0, 0, 0}, ss4[4] = {0, 0, 0, 0};
  float lgr[6][4];
#pragma unroll
  for (int m = 0; m < 6; m++) { lgr[m][0] = 0.f; lgr[m][1] = 0.f; lgr[m][2] = 0.f; lgr[m][3] = 0.f; }
#pragma unroll
  for (int r = 0; r < 10; r++) {
    int c = g * 40 + r * 4 + cg;
    float4 xv = *(const float4*)(fb + (size_t)(r * 4) * LL);
    float4 p03 = *(const float4*)&sh->P_s[c][0];
    float2 p45 = *(const float2*)&sh->P_s[c][4];
    float xs[4] = {xv.x, xv.y, xv.z, xv.w};
#pragma unroll
    for (int j = 0; j < 4; j++) {
      float x = xs[j];
      s4[j] += x; ss4[j] = fmaf(x, x, ss4[j]);
      lgr[0][j] = fmaf(x, p03.x, lgr[0][j]); lgr[1][j] = fmaf(x, p03.y, lgr[1][j]);
      lgr[2][j] = fmaf(x, p03.z, lgr[2][j]); lgr[3][j] = fmaf(x, p03.w, lgr[3][j]);
      lgr[4][j] = fmaf(x, p45.x, lgr[4][j]); lgr[5][j] = fmaf(x, p45.y, lgr[5][j]);
    }
    uint2 pk;
    pk.x = (unsigned int)f2bf(xv.x) | ((unsigned int)f2bf(xv.y) << 16);
    pk.y = (unsigned int)f2bf(xv.z) | ((unsigned int)f2bf(xv.w) << 16);
    *(uint2*)&sh->xb[c * XSTR + 4 * tl] = pk;
  }
#pragma unroll
  for (int j = 0; j < 4; j++) {
    s4[j] += __shfl_xor(s4[j], 16);  s4[j] += __shfl_xor(s4[j], 32);
    ss4[j] += __shfl_xor(ss4[j], 16); ss4[j] += __shfl_xor(ss4[j], 32);
#pragma unroll
    for (int m = 0; m < 6; m++) {
      lgr[m][j] += __shfl_xor(lgr[m][j], 16);
      lgr[m][j] += __shfl_xor(lgr[m][j], 32);
    }
  }
  if (cg == 0) {
#pragma unroll
    for (int j = 0; j < 4; j++) {
      float* pp = &sh->part[g][tl][j][0];
      *(float2*)&pp[0] = make_float2(s4[j], ss4[j]);
      *(float2*)&pp[2] = make_float2(lgr[0][j], lgr[1][j]);
      *(float2*)&pp[4] = make_float2(lgr[2][j], lgr[3][j]);
      *(float2*)&pp[6] = make_float2(lgr[4][j], lgr[5][j]);
    }
  }
  __syncthreads();
  {
    int tg = lane >> 2, tj = lane & 3;
    float S = 0.f, SS = 0.f, L[6] = {0, 0, 0, 0, 0, 0};
#pragma unroll
    for (int g2 = 0; g2 < 4; g2++) {
      const float* pp = &sh->part[g2][tg][tj][0];
      float2 a = *(const float2*)&pp[0];
      float2 b2_ = *(const float2*)&pp[2];
      float2 c2 = *(const float2*)&pp[4];
      float2 d2 = *(const float2*)&pp[6];
      S += a.x; SS += a.y;
      L[0] += b2_.x; L[1] += b2_.y; L[2] += c2.x; L[3] += c2.y; L[4] += d2.x; L[5] += d2.y;
    }
    float mu = S * (1.0f / CC);
    float var = SS * (1.0f / CC) - mu * mu;
    float rs = rsqrtf(var + 1e-5f);
    float lg[6];
#pragma unroll
    for (int m = 0; m < 6; m++) lg[m] = rs * L[m] - rs * mu * alpha[m] + beta[m];
    float mx = lg[0];
#pragma unroll
    for (int m = 1; m < 6; m++) mx = fmaxf(mx, lg[m]);
    float e[6], sum = 0.f;
#pragma unroll
    for (int m = 0; m < 6; m++) { e[m] = __expf(lg[m] - mx); sum += e[m]; }
    float inv = 1.0f / sum;
    float att[6], wv[6];
#pragma unroll
    for (int m = 0; m < 6; m++) { att[m] = e[m] * inv; wv[m] = att[m] * rs; }
    if (g == 0) {
      float wo[6];
#pragma unroll
      for (int m = 0; m < 6; m++) wo[m] = __shfl_xor(wv[m], 1);
      if (!(lane & 1)) {
        int tp = lane >> 1;
        unsigned int pk[6];
#pragma unroll
        for (int m = 0; m < 6; m++) pk[m] = (unsigned int)f2bf(wv[m]) | ((unsigned int)f2bf(wo[m]) << 16);
        *(uint4*)&sh->w2_s[tp][0] = make_uint4(pk[0], pk[1], pk[2], pk[3]);
        *(uint2*)&sh->w2_s[tp][4] = make_uint2(pk[4], pk[5]);
      }
    } else if (g == 1) {
      if (ITER2) {
#pragma unroll
        for (int m = 0; m < 6; m++) attn_out[attn_base + lane + (size_t)m * LL] = att[m];
      }
    } else if (g == 2) {
#pragma unroll
      for (int m = 0; m < 6; m++) Sacc[m] += att[m];
    } else {
#pragma unroll
      for (int m = 0; m < 6; m++) Sacc[m] += wv[m] * mu;
    }
  }
  __syncthreads();
  if (tid < DD) {
    const unsigned short* xr = &sh->xb[tid * XSTR];
#pragma unroll
    for (int k = 0; k < 16; k++) {
      uint2 xw = *(const uint2*)(xr + 4 * k);
      uint4 wa0 = *(const uint4*)&sh->w2_s[2 * k][0];
      uint2 wb0 = *(const uint2*)&sh->w2_s[2 * k][4];
      uint4 wa1 = *(const uint4*)&sh->w2_s[2 * k + 1][0];
      uint2 wb1 = *(const uint2*)&sh->w2_s[2 * k + 1][4];
      Aacc[0] = dot2bf(wa0.x, xw.x, Aacc[0]); Aacc[1] = dot2bf(wa0.y, xw.x, Aacc[1]);
      Aacc[2] = dot2bf(wa0.z, xw.x, Aacc[2]); Aacc[3] = dot2bf(wa0.w, xw.x, Aacc[3]);
      Aacc[4] = dot2bf(wb0.x, xw.x, Aacc[4]); Aacc[5] = dot2bf(wb0.y, xw.x, Aacc[5]);
      Aacc[0] = dot2bf(wa1.x, xw.y, Aacc[0]); Aacc[1] = dot2bf(wa1.y, xw.y, Aacc[1]);
      Aacc[2] = dot2bf(wa1.z, xw.y, Aacc[2]); Aacc[3] = dot2bf(wa1.w, xw.y, Aacc[3]);
      Aacc[4] = dot2bf(wb1.x, xw.y, Aacc[4]); Aacc[5] = dot2bf(wb1.y, xw.y, Aacc[5]);
    }
  }
  __syncthreads();
}

// ================= k_pass: 4 tiles/block, grid 1024 =================
template <bool ITER2>
__global__ __launch_bounds__(256) void k_pass(
    const float* __restrict__ feat, const float* __restrict__ Pg,
    const float* __restrict__ abg, float* __restrict__ Apart,
    float* __restrict__ SWpart, float* __restrict__ attn_out) {
  int b = blockIdx.x;
  int n = b >> 4, ch = b & 15;
  int tid = threadIdx.x;
  int lane = tid & 63, g = tid >> 6;
  int cg = lane >> 4, tl = lane & 15;
  __shared__ TileShared sh;

  const float* wsrc = ITER2 ? (Pg + (size_t)n * DD * 6) : Pg;
  for (int o = tid; o < DD * 6; o += 256) sh.P_s[o / 6][o % 6] = wsrc[o];
  const float* absrc = ITER2 ? (abg + n * 12) : abg;
  float alpha[6], beta[6];
#pragma unroll
  for (int m = 0; m < 6; m++) { alpha[m] = absrc[m]; beta[m] = absrc[6 + m]; }
  float Aacc[6] = {0, 0, 0, 0, 0, 0};
  float Sacc[6] = {0, 0, 0, 0, 0, 0};
  __syncthreads();

  const float* fb0 = feat + ((size_t)(n * CC + g * 40 + cg)) * LL + ch * (64 * NT) + 4 * tl;
#pragma unroll 1
  for (int t4 = 0; t4 < NT; t4++) {
    size_t ab_ = ((size_t)(n * MM)) * LL + ch * (64 * NT) + t4 * 64;
    tile_body<ITER2>(&sh, fb0 + t4 * 64, alpha, beta, tid, lane, g, cg, tl, Aacc, Sacc, attn_out, ab_);
  }
  if (g == 2 || g == 3) {
#pragma unroll
    for (int m = 0; m < 6; m++) {
      float v = Sacc[m];
      v += __shfl_xor(v, 1);  v += __shfl_xor(v, 2);  v += __shfl_xor(v, 4);
      v += __shfl_xor(v, 8);  v += __shfl_xor(v, 16); v += __shfl_xor(v, 32);
      if (lane == 0) SWpart[b * 12 + (g - 2) * 6 + m] = v;
    }
  }
  if (tid < DD) {
#pragma unroll
    for (int m = 0; m < 6; m++) Apart[((size_t)b * 6 + m) * DD + tid] = Aacc[m];
  }
}

// ================= k_slot4: transposed-weight slot tail, grid NN*MM =================
template <bool FIRST, bool LAST>
__global__ __launch_bounds__(256) void k_slot4(
    const float* __restrict__ slots_init, const float* __restrict__ Apart,
    const float* __restrict__ SWpart,
    const float* __restrict__ WvT, const float* __restrict__ WqT,
    const float* __restrict__ W1T, const float* __restrict__ W2T,
    const float* __restrict__ out_g, const float* __restrict__ out_b,
    const float* __restrict__ b1, const float* __restrict__ b2,
    const float* __restrict__ q_g, const float* __restrict__ q_b,
    const float* __restrict__ Wk,
    const float* __restrict__ kv_g, const float* __restrict__ kv_b,
    const float* __restrict__ scal,
    float* __restrict__ slotbuf, float* __restrict__ P2, float* __restrict__ ab2,
    float* __restrict__ Sfin, float* __restrict__ out_slots) {
  int b = blockIdx.x;
  int n = b / MM, m = b % MM;
  int tid = threadIdx.x;
  __shared__ float a_s[DD];
  __shared__ float s1[DD];
  __shared__ float h[320];
  __shared__ float pg[DD], pb[DD];
  __shared__ float sw_s[2];
  __shared__ float Sv_s, mu_s, rs_s;

  // P0: SW reduce
  if (tid < 32) {
    int p = tid & 15, which = tid >> 4;
    float v = SWpart[(size_t)(n * NCH + p) * 12 + m + 6 * which];
    v += __shfl_xor(v, 1); v += __shfl_xor(v, 2);
    v += __shfl_xor(v, 4); v += __shfl_xor(v, 8);
    if (p == 0) {
      sw_s[which] = v;
      if (which == 0) {
        float sc = fmaxf(v, 1e-6f);
        Sv_s = sc;
        if (LAST) Sfin[n * 6 + m] = sc;
      }
    }
  }
  __syncthreads();
  // P1: a = g*(Araw - W) + b*S (16 coalesced strided loads, fully unrolled)
  if (tid < DD) {
    const float* src = Apart + ((size_t)(n * NCH) * 6 + m) * DD + tid;
    float ar = 0.f;
#pragma unroll
    for (int p = 0; p < NCH; p++) ar += src[(size_t)p * 6 * DD];
    a_s[tid] = kv_g[tid] * (ar - sw_s[1]) + kv_b[tid] * sw_s[0];
  }
  __syncthreads();
  // P2: U = a @ Wv via WvT row stream
  if (tid < DD) {
    const float4* wr = (const float4*)(WvT + (size_t)tid * DD);
    float u = 0.f;
#pragma unroll 8
    for (int c4 = 0; c4 < 40; c4++) {
      float4 w = wr[c4];
      const float* ap = &a_s[c4 * 4];
      u = fmaf(w.x, ap[0], u); u = fmaf(w.y, ap[1], u);
      u = fmaf(w.z, ap[2], u); u = fmaf(w.w, ap[3], u);
    }
    float prev = FIRST ? slots_init[m * DD + tid] : slotbuf[(size_t)n * MM * DD + m * DD + tid];
    s1[tid] = prev + u / Sv_s;
  }
  __syncthreads();
  // P3: LN
  if (tid < 64) {
    float x0 = s1[tid], x1 = s1[tid + 64], x2 = (tid < 32) ? s1[tid + 128] : 0.f;
    float s = x0 + x1 + x2, ss = x0 * x0 + x1 * x1 + x2 * x2;
#pragma unroll
    for (int off = 32; off >= 1; off >>= 1) { s += __shfl_xor(s, off); ss += __shfl_xor(ss, off); }
    if (tid == 0) {
      float mu = s / DD, var = ss / DD - mu * mu;
      mu_s = mu; rs_s = rsqrtf(var + 1e-5f);
    }
  }
  __syncthreads();
  if (tid < DD) s1[tid] = (s1[tid] - mu_s) * rs_s * out_g[tid] + out_b[tid];
  __syncthreads();
  // P4: MLP hidden via W1T row stream (320 outs over 256 threads)
  for (int j = tid; j < 320; j += 256) {
    const float4* wr = (const float4*)(W1T + (size_t)j * DD);
    float acc = b1[j];
#pragma unroll 8
    for (int d4 = 0; d4 < 40; d4++) {
      float4 w = wr[d4];
      const float* sp = &s1[d4 * 4];
      acc = fmaf(w.x, sp[0], acc); acc = fmaf(w.y, sp[1], acc);
      acc = fmaf(w.z, sp[2], acc); acc = fmaf(w.w, sp[3], acc);
    }
    h[j] = 0.5f * acc * (1.0f + erff(acc * 0.70710678118f));
  }
  __syncthreads();
  // P5: MLP out via W2T row stream + residual
  if (tid < DD) {
    const float4* wr = (const float4*)(W2T + (size_t)tid * 320);
    float acc = b2[tid];
#pragma unroll 8
    for (int j4 = 0; j4 < 80; j4++) {
      float4 w = wr[j4];
      const float* hp = &h[j4 * 4];
      acc = fmaf(w.x, hp[0], acc); acc = fmaf(w.y, hp[1], acc);
      acc = fmaf(w.z, hp[2], acc); acc = fmaf(w.w, hp[3], acc);
    }
    float val = s1[tid] + acc;
    a_s[tid] = val;
    if (LAST) out_slots[(size_t)n * MM * DD + m * DD + tid] = val;
    else slotbuf[(size_t)n * MM * DD + m * DD + tid] = val;
  }
  if (!LAST) {
    __syncthreads();
    // P6: q-LN stats
    if (tid < 64) {
      float x0 = a_s[tid], x1 = a_s[tid + 64], x2 = (tid < 32) ? a_s[tid + 128] : 0.f;
      float s = x0 + x1 + x2, ss = x0 * x0 + x1 * x1 + x2 * x2;
#pragma unroll
      for (int off = 32; off >= 1; off >>= 1) { s += __shfl_xor(s, off); ss += __shfl_xor(ss, off); }
      if (tid == 0) {
        float mu = s / DD, var = ss / DD - mu * mu;
        mu_s = mu; rs_s = rsqrtf(var + 1e-5f);
      }
    }
    __syncthreads();
    if (tid < DD) s1[tid] = (a_s[tid] - mu_s) * rs_s * q_g[tid] + q_b[tid];
    __syncthreads();
    // P7: q = ln @ Wq via WqT row stream
    if (tid < DD) {
      const float4* wr = (const float4*)(WqT + (size_t)tid * DD);
      float acc = 0.f;
#pragma unroll 8
      for (int i4 = 0; i4 < 40; i4++) {
        float4 w = wr[i4];
        const float* sp = &s1[i4 * 4];
        acc = fmaf(w.x, sp[0], acc); acc = fmaf(w.y, sp[1], acc);
        acc = fmaf(w.z, sp[2], acc); acc = fmaf(w.w, sp[3], acc);
      }
      h[tid] = acc;
    }
    __syncthreads();
    // P8: Wkq column m via row-major Wk row stream (thread = c)
    if (tid < DD) {
      const float4* wr = (const float4*)(Wk + (size_t)tid * DD);
      float s = 0.f;
#pragma unroll 8
      for (int d4 = 0; d4 < 40; d4++) {
        float4 w = wr[d4];
        const float* hp = &h[d4 * 4];
        s = fmaf(w.x, hp[0], s); s = fmaf(w.y, hp[1], s);
        s = fmaf(w.z, hp[2], s); s = fmaf(w.w, hp[3], s);
      }
      float wrv = scal[0] * s;
      float gv = kv_g[tid] * wrv;
      P2[(size_t)n * DD * 6 + tid * 6 + m] = gv;
      pg[tid] = gv;
      pb[tid] = kv_b[tid] * wrv;
    }
    __syncthreads();
    // P9: ab2
    if (tid < 128) {
      int w = tid >> 6, l = tid & 63;
      const float* src = (w == 0) ? pg : pb;
      float x0 = src[l], x1 = src[l + 64], x2 = (l < 32) ? src[l + 128] : 0.f;
      float s = x0 + x1 + x2;
#pragma unroll
      for (int off = 32; off >= 1; off >>= 1) s += __shfl_xor(s, off);
      if (l == 0) ab2[n * 12 + 6 * w + m] = s;
    }
  }
}

// ================= k_norm =================
__global__ __launch_bounds__(256) void k_norm(float* attn, const float* Sfin) {
  int idx = blockIdx.x * 256 + threadIdx.x;
  size_t base = (size_t)idx * 4;
  int nm = (int)(base >> 12);
  float s = Sfin[nm];
  float4 v = *(float4*)(attn + base);
  float inv = 1.0f / s;
  v.x *= inv; v.y *= inv; v.z *= inv; v.w *= inv;
  *(float4*)(attn + base) = v;
}

extern "C" void kernel_launch(void* const* d_in, const int* in_sizes, int n_in,
                              void* d_out, int out_size, void* d_ws, size_t ws_size,
                              hipStream_t stream) {
  const float* feat       = (const float*)d_in[0];
  const float* slots_init = (const float*)d_in[1];
  const float* log_tau    = (const float*)d_in[2];
  const float* kv_g       = (const float*)d_in[3];
  const float* kv_b       = (const float*)d_in[4];
  const float* Wk         = (const float*)d_in[5];
  const float* Wv         = (const float*)d_in[6];
  const float* q_g        = (const float*)d_in[7];
  const float* q_b        = (const float*)d_in[8];
  const float* Wq         = (const float*)d_in[9];
  const float* out_g      = (const float*)d_in[10];
  const float* out_b      = (const float*)d_in[11];
  const float* W1         = (const float*)d_in[12];
  const float* b1         = (const float*)d_in[13];
  const float* W2         = (const float*)d_in[14];
  const float* b2         = (const float*)d_in[15];
  float* out = (float*)d_out;
  float* out_attn = out + NN * MM * DD;

  float* Wkq1   = (float*)d_ws;                          // [960]
  float* ab     = Wkq1 + DD * 6;                         // [12] (pad 16)
  float* P1     = ab + 16;                               // [960]
  float* P2     = P1 + DD * 6;                           // [64][960]
  float* ab2    = P2 + (size_t)NN * DD * 6;              // [64][12]
  float* Apart  = ab2 + NN * 12;                         // [1024][6][160]
  float* SWpart = Apart + (size_t)NN * NCH * MM * DD;    // [1024][12]
  float* Sfin   = SWpart + (size_t)NN * NCH * 12;        // [64][6]
  float* scal   = Sfin + NN * MM;                        // [1] (pad 8)
  float* slotbuf = scal + 8;                             // [64][6][160]
  float* WvT    = slotbuf + NN * MM * DD;                // [160*160]
  float* WqT    = WvT + DD * DD;                         // [160*160]
  float* W1T    = WqT + DD * DD;                         // [320*160]
  float* W2T    = W1T + DD * 320;                        // [160*320]
  size_t required = (size_t)((char*)(W2T + DD * 320) - (char*)d_ws);
  if (ws_size < required) return;

  k_trans<<<150, 256, 0, stream>>>(Wv, Wq, W1, W2, WvT, WqT, W1T, W2T);
  k_init<<<16, 512, 0, stream>>>(log_tau, slots_init, q_g, q_b, Wq, Wk, Wkq1, scal);
  k_init2<<<1, 256, 0, stream>>>(Wkq1, kv_g, kv_b, P1, ab);
  k_pass<false><<<NN * NCH, 256, 0, stream>>>(feat, P1, ab, Apart, SWpart, out_attn);
  k_slot4<true, false><<<NN * MM, 256, 0, stream>>>(slots_init, Apart, SWpart, WvT, WqT, W1T, W2T,
                                                    out_g, out_b, b1, b2, q_g, q_b, Wk, kv_g, kv_b,
                                                    scal, slotbuf, P2, ab2, Sfin, out);
  k_pass<true><<<NN * NCH, 256, 0, stream>>>(feat, P2, ab2, Apart, SWpart, out_attn);
  k_slot4<false, true><<<NN * MM, 256, 0, stream>>>(slots_init, Apart, SWpart, WvT, WqT, W1T, W2T,
                                                    out_g, out_b, b1, b2, q_g, q_b, Wk, kv_g, kv_b,
                                                    scal, slotbuf, P2, ab2, Sfin, out);
  k_norm<<<(NN * MM * LL) / 1024, 256, 0, stream>>>(out_attn, Sfin);
}

// Round 21
// 206.836 us; speedup vs baseline: 3.7983x; 1.0160x over previous
//
#include <hip/hip_runtime.h>
#include <math.h>

#define NN 64
#define CC 160
#define LL 4096
#define DD 160
#define MM 6
#define NCH 16      // chunks per image; chunk = 256 tokens = 4 tiles of 64
#define NT 4
#define XSTR 68     // xb row stride in tokens (136B: b64 conflict-free)

#if defined(__has_builtin)
#if __has_builtin(__builtin_amdgcn_fdot2_f32_bf16)
#define HAVE_DOT2 1
#endif
#endif

__device__ __forceinline__ unsigned short f2bf(float f) {
  union { float f; unsigned int i; } v; v.f = f;
  unsigned int r = v.i + 0x7fffu + ((v.i >> 16) & 1u);
  return (unsigned short)(r >> 16);
}
__device__ __forceinline__ float u2f_lo(unsigned int w) {
  union { unsigned int i; float f; } v; v.i = w << 16; return v.f;
}
__device__ __forceinline__ float u2f_hi(unsigned int w) {
  union { unsigned int i; float f; } v; v.i = w & 0xffff0000u; return v.f;
}

#if HAVE_DOT2
typedef __bf16 v2bf __attribute__((ext_vector_type(2)));
__device__ __forceinline__ float dot2bf(unsigned int a, unsigned int b, float c) {
  union { unsigned int u; v2bf v; } ua, ub;
  ua.u = a; ub.u = b;
  return __builtin_amdgcn_fdot2_f32_bf16(ua.v, ub.v, c, false);
}
#else
__device__ __forceinline__ float dot2bf(unsigned int a, unsigned int b, float c) {
  return fmaf(u2f_hi(a), u2f_hi(b), fmaf(u2f_lo(a), u2f_lo(b), c));
}
#endif

// ================= k_setup: blocks 0-149 transpose weights; block 150 = init + init2 =================
__global__ __launch_bounds__(512) void k_setup(
    const float* __restrict__ Wv, const float* __restrict__ Wq,
    const float* __restrict__ W1, const float* __restrict__ W2,
    const float* __restrict__ log_tau, const float* __restrict__ slots_init,
    const float* __restrict__ q_g, const float* __restrict__ q_b,
    const float* __restrict__ Wk, const float* __restrict__ kv_g, const float* __restrict__ kv_b,
    float* __restrict__ WvT, float* __restrict__ WqT,
    float* __restrict__ W1T, float* __restrict__ W2T,
    float* __restrict__ P1, float* __restrict__ ab, float* __restrict__ scal) {
  int b = blockIdx.x;
  int tid = threadIdx.x;
  if (b < 150) {
    const float* src; float* dst; int R, C, tr, tc;
    if (b < 25)       { src = Wv; dst = WvT; R = 160; C = 160; int t = b;       tr = t / 5;  tc = t % 5; }
    else if (b < 50)  { src = Wq; dst = WqT; R = 160; C = 160; int t = b - 25;  tr = t / 5;  tc = t % 5; }
    else if (b < 100) { src = W1; dst = W1T; R = 160; C = 320; int t = b - 50;  tr = t / 10; tc = t % 10; }
    else              { src = W2; dst = W2T; R = 320; C = 160; int t = b - 100; tr = t / 5;  tc = t % 5; }
    __shared__ float tile[32][33];
    int r0 = tr * 32, c0 = tc * 32;
    int lr = tid >> 5, lc = tid & 31;   // lr 0..15
#pragma unroll
    for (int i = 0; i < 2; i++)
      tile[lr + i * 16][lc] = src[(size_t)(r0 + lr + i * 16) * C + c0 + lc];
    __syncthreads();
#pragma unroll
    for (int i = 0; i < 2; i++)
      dst[(size_t)(c0 + lr + i * 16) * R + r0 + lc] = tile[lc][lr + i * 16];
    return;
  }
  // ---- block 150: full init chain ----
  __shared__ float ln[MM * DD];
  __shared__ float qv[MM * DD];
  __shared__ float pgb[MM * DD];   // P1 values (g*wr), [c][m] flat c*6+m
  __shared__ float pbb[MM * DD];   // b*wr
  __shared__ float mu_s[MM], rs_s[MM];
  float x = log_tau[0];
  float sp = (x > 20.f) ? x : log1pf(expf(x));
  float scv = (1.0f / sqrtf((float)DD)) / (sp + 0.5f);
  if (tid == 0) scal[0] = scv;
  int w = tid >> 6, l = tid & 63;
  if (w < MM) {
    float x0 = slots_init[w * DD + l];
    float x1 = slots_init[w * DD + l + 64];
    float x2 = (l < 32) ? slots_init[w * DD + l + 128] : 0.f;
    float s = x0 + x1 + x2, ss = x0 * x0 + x1 * x1 + x2 * x2;
#pragma unroll
    for (int off = 32; off >= 1; off >>= 1) { s += __shfl_xor(s, off); ss += __shfl_xor(ss, off); }
    if (l == 0) {
      float mu = s / DD, var = ss / DD - mu * mu;
      mu_s[w] = mu; rs_s[w] = rsqrtf(var + 1e-5f);
    }
  }
  __syncthreads();
  for (int o = tid; o < MM * DD; o += 512) {
    int m = o / DD, d = o % DD;
    ln[o] = (slots_init[o] - mu_s[m]) * rs_s[m] * q_g[d] + q_b[d];
  }
  __syncthreads();
  for (int o = tid; o < MM * DD; o += 512) {
    int m = o / DD, d = o % DD;
    float acc = 0.f;
#pragma unroll 8
    for (int i = 0; i < DD; i++) acc = fmaf(ln[m * DD + i], Wq[i * DD + d], acc);
    qv[o] = acc;
  }
  __syncthreads();
  // Wkq1 -> P1 + stage pg/pb for ab reduction
  for (int o = tid; o < MM * DD; o += 512) {
    int c = o / 6, m = o % 6;
    const float4* wr = (const float4*)(Wk + (size_t)c * DD);
    const float* qm = &qv[m * DD];
    float s = 0.f;
#pragma unroll 8
    for (int d4 = 0; d4 < 40; d4++) {
      float4 wv4 = wr[d4];
      s = fmaf(wv4.x, qm[d4 * 4], s);     s = fmaf(wv4.y, qm[d4 * 4 + 1], s);
      s = fmaf(wv4.z, qm[d4 * 4 + 2], s); s = fmaf(wv4.w, qm[d4 * 4 + 3], s);
    }
    float wrv = scv * s;
    float gv = kv_g[c] * wrv;
    P1[o] = gv;
    pgb[o] = gv;
    pbb[o] = kv_b[c] * wrv;
  }
  __syncthreads();
  if (tid < 384) {
    int grp = tid >> 5;      // 0..11
    int l5 = tid & 31;
    int m = grp % 6;
    const float* src = (grp < 6) ? pgb : pbb;
    float s = 0.f;
#pragma unroll
    for (int i = 0; i < 5; i++) s += src[(l5 + i * 32) * 6 + m];
    s += __shfl_xor(s, 1); s += __shfl_xor(s, 2); s += __shfl_xor(s, 4);
    s += __shfl_xor(s, 8); s += __shfl_xor(s, 16);
    if (l5 == 0) ab[grp] = s;
  }
}

// ================= k_pass: 4 tiles/block, grid 1024; 5-load batches in phase 0 =================
struct TileShared {
  unsigned short xb[160 * XSTR];
  float part[4][16][4][10];
  unsigned int w2_s[32][8];
  float P_s[160][8];
};

template <bool ITER2>
__global__ __launch_bounds__(256) void k_pass(
    const float* __restrict__ feat, const float* __restrict__ Pg,
    const float* __restrict__ abg, float* __restrict__ Apart,
    float* __restrict__ SWpart, float* __restrict__ attn_out) {
  int b = blockIdx.x;
  int n = b >> 4, ch = b & 15;
  int tid = threadIdx.x;
  int lane = tid & 63, g = tid >> 6;
  int cg = lane >> 4, tl = lane & 15;
  __shared__ TileShared sh;

  const float* wsrc = ITER2 ? (Pg + (size_t)n * DD * 6) : Pg;
  for (int o = tid; o < DD * 6; o += 256) sh.P_s[o / 6][o % 6] = wsrc[o];
  const float* absrc = ITER2 ? (abg + n * 12) : abg;
  float alpha[6], beta[6];
#pragma unroll
  for (int m = 0; m < 6; m++) { alpha[m] = absrc[m]; beta[m] = absrc[6 + m]; }
  float Aacc[6] = {0, 0, 0, 0, 0, 0};
  float Sacc[6] = {0, 0, 0, 0, 0, 0};
  __syncthreads();

  const float* fb0 = feat + ((size_t)(n * CC + g * 40 + cg)) * LL + ch * (64 * NT) + 4 * tl;

#pragma unroll 1
  for (int t4 = 0; t4 < NT; t4++) {
    const float* fb = fb0 + t4 * 64;
    float s4[4] = {0, 0, 0, 0}, ss4[4] = {0, 0, 0, 0};
    float lgr[6][4];
#pragma unroll
    for (int m = 0; m < 6; m++) { lgr[m][0] = 0.f; lgr[m][1] = 0.f; lgr[m][2] = 0.f; lgr[m][3] = 0.f; }
#pragma unroll
    for (int h5 = 0; h5 < 2; h5++) {
      float4 xv[5];
#pragma unroll
      for (int r5 = 0; r5 < 5; r5++)
        xv[r5] = *(const float4*)(fb + (size_t)((h5 * 5 + r5) * 4) * LL);
#pragma unroll
      for (int r5 = 0; r5 < 5; r5++) {
        int r = h5 * 5 + r5;
        int c = g * 40 + r * 4 + cg;
        float4 p03 = *(const float4*)&sh.P_s[c][0];
        float2 p45 = *(const float2*)&sh.P_s[c][4];
        float xs[4] = {xv[r5].x, xv[r5].y, xv[r5].z, xv[r5].w};
#pragma unroll
        for (int j = 0; j < 4; j++) {
          float xx = xs[j];
          s4[j] += xx; ss4[j] = fmaf(xx, xx, ss4[j]);
          lgr[0][j] = fmaf(xx, p03.x, lgr[0][j]); lgr[1][j] = fmaf(xx, p03.y, lgr[1][j]);
          lgr[2][j] = fmaf(xx, p03.z, lgr[2][j]); lgr[3][j] = fmaf(xx, p03.w, lgr[3][j]);
          lgr[4][j] = fmaf(xx, p45.x, lgr[4][j]); lgr[5][j] = fmaf(xx, p45.y, lgr[5][j]);
        }
        uint2 pk;
        pk.x = (unsigned int)f2bf(xv[r5].x) | ((unsigned int)f2bf(xv[r5].y) << 16);
        pk.y = (unsigned int)f2bf(xv[r5].z) | ((unsigned int)f2bf(xv[r5].w) << 16);
        *(uint2*)&sh.xb[c * XSTR + 4 * tl] = pk;
      }
    }
#pragma unroll
    for (int j = 0; j < 4; j++) {
      s4[j] += __shfl_xor(s4[j], 16);  s4[j] += __shfl_xor(s4[j], 32);
      ss4[j] += __shfl_xor(ss4[j], 16); ss4[j] += __shfl_xor(ss4[j], 32);
#pragma unroll
      for (int m = 0; m < 6; m++) {
        lgr[m][j] += __shfl_xor(lgr[m][j], 16);
        lgr[m][j] += __shfl_xor(lgr[m][j], 32);
      }
    }
    if (cg == 0) {
#pragma unroll
      for (int j = 0; j < 4; j++) {
        float* pp = &sh.part[g][tl][j][0];
        *(float2*)&pp[0] = make_float2(s4[j], ss4[j]);
        *(float2*)&pp[2] = make_float2(lgr[0][j], lgr[1][j]);
        *(float2*)&pp[4] = make_float2(lgr[2][j], lgr[3][j]);
        *(float2*)&pp[6] = make_float2(lgr[4][j], lgr[5][j]);
      }
    }
    __syncthreads();
    {
      int tg = lane >> 2, tj = lane & 3;
      float S = 0.f, SS = 0.f, L[6] = {0, 0, 0, 0, 0, 0};
#pragma unroll
      for (int g2 = 0; g2 < 4; g2++) {
        const float* pp = &sh.part[g2][tg][tj][0];
        float2 a = *(const float2*)&pp[0];
        float2 b2_ = *(const float2*)&pp[2];
        float2 c2 = *(const float2*)&pp[4];
        float2 d2 = *(const float2*)&pp[6];
        S += a.x; SS += a.y;
        L[0] += b2_.x; L[1] += b2_.y; L[2] += c2.x; L[3] += c2.y; L[4] += d2.x; L[5] += d2.y;
      }
      float mu = S * (1.0f / CC);
      float var = SS * (1.0f / CC) - mu * mu;
      float rs = rsqrtf(var + 1e-5f);
      float lg[6];
#pragma unroll
      for (int m = 0; m < 6; m++) lg[m] = rs * L[m] - rs * mu * alpha[m] + beta[m];
      float mx = lg[0];
#pragma unroll
      for (int m = 1; m < 6; m++) mx = fmaxf(mx, lg[m]);
      float e[6], sum = 0.f;
#pragma unroll
      for (int m = 0; m < 6; m++) { e[m] = __expf(lg[m] - mx); sum += e[m]; }
      float inv = 1.0f / sum;
      float att[6], wv[6];
#pragma unroll
      for (int m = 0; m < 6; m++) { att[m] = e[m] * inv; wv[m] = att[m] * rs; }
      if (g == 0) {
        float wo[6];
#pragma unroll
        for (int m = 0; m < 6; m++) wo[m] = __shfl_xor(wv[m], 1);
        if (!(lane & 1)) {
          int tp = lane >> 1;
          unsigned int pk[6];
#pragma unroll
          for (int m = 0; m < 6; m++) pk[m] = (unsigned int)f2bf(wv[m]) | ((unsigned int)f2bf(wo[m]) << 16);
          *(uint4*)&sh.w2_s[tp][0] = make_uint4(pk[0], pk[1], pk[2], pk[3]);
          *(uint2*)&sh.w2_s[tp][4] = make_uint2(pk[4], pk[5]);
        }
      } else if (g == 1) {
        if (ITER2) {
          size_t ob = ((size_t)(n * MM)) * LL + ch * (64 * NT) + t4 * 64 + lane;
#pragma unroll
          for (int m = 0; m < 6; m++) attn_out[ob + (size_t)m * LL] = att[m];
        }
      } else if (g == 2) {
#pragma unroll
        for (int m = 0; m < 6; m++) Sacc[m] += att[m];
      } else {
#pragma unroll
        for (int m = 0; m < 6; m++) Sacc[m] += wv[m] * mu;
      }
    }
    __syncthreads();
    if (tid < DD) {
      const unsigned short* xr = &sh.xb[tid * XSTR];
#pragma unroll
      for (int k = 0; k < 16; k++) {
        uint2 xw = *(const uint2*)(xr + 4 * k);
        uint4 wa0 = *(const uint4*)&sh.w2_s[2 * k][0];
        uint2 wb0 = *(const uint2*)&sh.w2_s[2 * k][4];
        uint4 wa1 = *(const uint4*)&sh.w2_s[2 * k + 1][0];
        uint2 wb1 = *(const uint2*)&sh.w2_s[2 * k + 1][4];
        Aacc[0] = dot2bf(wa0.x, xw.x, Aacc[0]); Aacc[1] = dot2bf(wa0.y, xw.x, Aacc[1]);
        Aacc[2] = dot2bf(wa0.z, xw.x, Aacc[2]); Aacc[3] = dot2bf(wa0.w, xw.x, Aacc[3]);
        Aacc[4] = dot2bf(wb0.x, xw.x, Aacc[4]); Aacc[5] = dot2bf(wb0.y, xw.x, Aacc[5]);
        Aacc[0] = dot2bf(wa1.x, xw.y, Aacc[0]); Aacc[1] = dot2bf(wa1.y, xw.y, Aacc[1]);
        Aacc[2] = dot2bf(wa1.z, xw.y, Aacc[2]); Aacc[3] = dot2bf(wa1.w, xw.y, Aacc[3]);
        Aacc[4] = dot2bf(wb1.x, xw.y, Aacc[4]); Aacc[5] = dot2bf(wb1.y, xw.y, Aacc[5]);
      }
    }
    __syncthreads();
  }

  if (g == 2 || g == 3) {
#pragma unroll
    for (int m = 0; m < 6; m++) {
      float v = Sacc[m];
      v += __shfl_xor(v, 1);  v += __shfl_xor(v, 2);  v += __shfl_xor(v, 4);
      v += __shfl_xor(v, 8);  v += __shfl_xor(v, 16); v += __shfl_xor(v, 32);
      if (lane == 0) SWpart[b * 12 + (g - 2) * 6 + m] = v;
    }
  }
  if (tid < DD) {
#pragma unroll
    for (int m = 0; m < 6; m++) Apart[((size_t)b * 6 + m) * DD + tid] = Aacc[m];
  }
}

// ================= k_slot4: transposed-weight slot tail (+fused attn-norm on LAST) =================
template <bool FIRST, bool LAST>
__global__ __launch_bounds__(256) void k_slot4(
    const float* __restrict__ slots_init, const float* __restrict__ Apart,
    const float* __restrict__ SWpart,
    const float* __restrict__ WvT, const float* __restrict__ WqT,
    const float* __restrict__ W1T, const float* __restrict__ W2T,
    const float* __restrict__ out_g, const float* __restrict__ out_b,
    const float* __restrict__ b1, const float* __restrict__ b2,
    const float* __restrict__ q_g, const float* __restrict__ q_b,
    const float* __restrict__ Wk,
    const float* __restrict__ kv_g, const float* __restrict__ kv_b,
    const float* __restrict__ scal,
    float* __restrict__ slotbuf, float* __restrict__ P2, float* __restrict__ ab2,
    float* __restrict__ out_slots, float* __restrict__ attn) {
  int b = blockIdx.x;
  int n = b / MM, m = b % MM;
  int tid = threadIdx.x;
  __shared__ float a_s[DD];
  __shared__ float s1[DD];
  __shared__ float h[320];
  __shared__ float pg[DD], pb[DD];
  __shared__ float sw_s[2];
  __shared__ float Sv_s, mu_s, rs_s;

  if (tid < 32) {
    int p = tid & 15, which = tid >> 4;
    float v = SWpart[(size_t)(n * NCH + p) * 12 + m + 6 * which];
    v += __shfl_xor(v, 1); v += __shfl_xor(v, 2);
    v += __shfl_xor(v, 4); v += __shfl_xor(v, 8);
    if (p == 0) {
      sw_s[which] = v;
      if (which == 0) Sv_s = fmaxf(v, 1e-6f);
    }
  }
  __syncthreads();
  if (tid < DD) {
    const float* src = Apart + ((size_t)(n * NCH) * 6 + m) * DD + tid;
    float ar = 0.f;
#pragma unroll
    for (int p = 0; p < NCH; p++) ar += src[(size_t)p * 6 * DD];
    a_s[tid] = kv_g[tid] * (ar - sw_s[1]) + kv_b[tid] * sw_s[0];
  }
  __syncthreads();
  if (tid < DD) {
    const float4* wr = (const float4*)(WvT + (size_t)tid * DD);
    float u = 0.f;
#pragma unroll 8
    for (int c4 = 0; c4 < 40; c4++) {
      float4 w = wr[c4];
      const float* ap = &a_s[c4 * 4];
      u = fmaf(w.x, ap[0], u); u = fmaf(w.y, ap[1], u);
      u = fmaf(w.z, ap[2], u); u = fmaf(w.w, ap[3], u);
    }
    float prev = FIRST ? slots_init[m * DD + tid] : slotbuf[(size_t)n * MM * DD + m * DD + tid];
    s1[tid] = prev + u / Sv_s;
  }
  __syncthreads();
  if (tid < 64) {
    float x0 = s1[tid], x1 = s1[tid + 64], x2 = (tid < 32) ? s1[tid + 128] : 0.f;
    float s = x0 + x1 + x2, ss = x0 * x0 + x1 * x1 + x2 * x2;
#pragma unroll
    for (int off = 32; off >= 1; off >>= 1) { s += __shfl_xor(s, off); ss += __shfl_xor(ss, off); }
    if (tid == 0) {
      float mu = s / DD, var = ss / DD - mu * mu;
      mu_s = mu; rs_s = rsqrtf(var + 1e-5f);
    }
  }
  __syncthreads();
  if (tid < DD) s1[tid] = (s1[tid] - mu_s) * rs_s * out_g[tid] + out_b[tid];
  __syncthreads();
  for (int j = tid; j < 320; j += 256) {
    const float4* wr = (const float4*)(W1T + (size_t)j * DD);
    float acc = b1[j];
#pragma unroll 8
    for (int d4 = 0; d4 < 40; d4++) {
      float4 w = wr[d4];
      const float* sp = &s1[d4 * 4];
      acc = fmaf(w.x, sp[0], acc); acc = fmaf(w.y, sp[1], acc);
      acc = fmaf(w.z, sp[2], acc); acc = fmaf(w.w, sp[3], acc);
    }
    h[j] = 0.5f * acc * (1.0f + erff(acc * 0.70710678118f));
  }
  __syncthreads();
  if (tid < DD) {
    const float4* wr = (const float4*)(W2T + (size_t)tid * 320);
    float acc = b2[tid];
#pragma unroll 8
    for (int j4 = 0; j4 < 80; j4++) {
      float4 w = wr[j4];
      const float* hp = &h[j4 * 4];
      acc = fmaf(w.x, hp[0], acc); acc = fmaf(w.y, hp[1], acc);
      acc = fmaf(w.z, hp[2], acc); acc = fmaf(w.w, hp[3], acc);
    }
    float val = s1[tid] + acc;
    a_s[tid] = val;
    if (LAST) out_slots[(size_t)n * MM * DD + m * DD + tid] = val;
    else slotbuf[(size_t)n * MM * DD + m * DD + tid] = val;
  }
  if (LAST) {
    // fused attn normalization: this block owns row (n,m) of attn
    float inv = 1.0f / Sv_s;
    float4* arow = (float4*)(attn + ((size_t)(n * MM + m)) * LL);
#pragma unroll
    for (int i = tid; i < LL / 4; i += 256) {
      float4 v = arow[i];
      v.x *= inv; v.y *= inv; v.z *= inv; v.w *= inv;
      arow[i] = v;
    }
  } else {
    __syncthreads();
    if (tid < 64) {
      float x0 = a_s[tid], x1 = a_s[tid + 64], x2 = (tid < 32) ? a_s[tid + 128] : 0.f;
      float s = x0 + x1 + x2, ss = x0 * x0 + x1 * x1 + x2 * x2;
#pragma unroll
      for (int off = 32; off >= 1; off >>= 1) { s += __shfl_xor(s, off); ss += __shfl_xor(ss, off); }
      if (tid == 0) {
        float mu = s / DD, var = ss / DD - mu * mu;
        mu_s = mu; rs_s = rsqrtf(var + 1e-5f);
      }
    }
    __syncthreads();
    if (tid < DD) s1[tid] = (a_s[tid] - mu_s) * rs_s * q_g[tid] + q_b[tid];
    __syncthreads();
    if (tid < DD) {
      const float4* wr = (const float4*)(WqT + (size_t)tid * DD);
      float acc = 0.f;
#pragma unroll 8
      for (int i4 = 0; i4 < 40; i4++) {
        float4 w = wr[i4];
        const float* sp = &s1[i4 * 4];
        acc = fmaf(w.x, sp[0], acc); acc = fmaf(w.y, sp[1], acc);
        acc = fmaf(w.z, sp[2], acc); acc = fmaf(w.w, sp[3], acc);
      }
      h[tid] = acc;
    }
    __syncthreads();
    if (tid < DD) {
      const float4* wr = (const float4*)(Wk + (size_t)tid * DD);
      float s = 0.f;
#pragma unroll 8
      for (int d4 = 0; d4 < 40; d4++) {
        float4 w = wr[d4];
        const float* hp = &h[d4 * 4];
        s = fmaf(w.x, hp[0], s); s = fmaf(w.y, hp[1], s);
        s = fmaf(w.z, hp[2], s); s = fmaf(w.w, hp[3], s);
      }
      float wrv = scal[0] * s;
      float gv = kv_g[tid] * wrv;
      P2[(size_t)n * DD * 6 + tid * 6 + m] = gv;
      pg[tid] = gv;
      pb[tid] = kv_b[tid] * wrv;
    }
    __syncthreads();
    if (tid < 128) {
      int w = tid >> 6, l = tid & 63;
      const float* src = (w == 0) ? pg : pb;
      float x0 = src[l], x1 = src[l + 64], x2 = (l < 32) ? src[l + 128] : 0.f;
      float s = x0 + x1 + x2;
#pragma unroll
      for (int off = 32; off >= 1; off >>= 1) s += __shfl_xor(s, off);
      if (l == 0) ab2[n * 12 + 6 * w + m] = s;
    }
  }
}

extern "C" void kernel_launch(void* const* d_in, const int* in_sizes, int n_in,
                              void* d_out, int out_size, void* d_ws, size_t ws_size,
                              hipStream_t stream) {
  const float* feat       = (const float*)d_in[0];
  const float* slots_init = (const float*)d_in[1];
  const float* log_tau    = (const float*)d_in[2];
  const float* kv_g       = (const float*)d_in[3];
  const float* kv_b       = (const float*)d_in[4];
  const float* Wk         = (const float*)d_in[5];
  const float* Wv         = (const float*)d_in[6];
  const float* q_g        = (const float*)d_in[7];
  const float* q_b        = (const float*)d_in[8];
  const float* Wq         = (const float*)d_in[9];
  const float* out_g      = (const float*)d_in[10];
  const float* out_b      = (const float*)d_in[11];
  const float* W1         = (const float*)d_in[12];
  const float* b1         = (const float*)d_in[13];
  const float* W2         = (const float*)d_in[14];
  const float* b2         = (const float*)d_in[15];
  float* out = (float*)d_out;
  float* out_attn = out + NN * MM * DD;

  float* ab     = (float*)d_ws;                          // [12] (pad 16)
  float* P1     = ab + 16;                               // [960]
  float* P2     = P1 + DD * 6;                           // [64][960]
  float* ab2    = P2 + (size_t)NN * DD * 6;              // [64][12]
  float* Apart  = ab2 + NN * 12;                         // [1024][6][160]
  float* SWpart = Apart + (size_t)NN * NCH * MM * DD;    // [1024][12]
  float* scal   = SWpart + (size_t)NN * NCH * 12;        // [1] (pad 8)
  float* slotbuf = scal + 8;                             // [64][6][160]
  float* WvT    = slotbuf + NN * MM * DD;                // [160*160]
  float* WqT    = WvT + DD * DD;                         // [160*160]
  float* W1T    = WqT + DD * DD;                         // [320*160]
  float* W2T    = W1T + DD * 320;                        // [160*320]
  size_t required = (size_t)((char*)(W2T + DD * 320) - (char*)d_ws);
  if (ws_size < required) return;

  k_setup<<<151, 512, 0, stream>>>(Wv, Wq, W1, W2, log_tau, slots_init, q_g, q_b,
                                   Wk, kv_g, kv_b, WvT, WqT, W1T, W2T, P1, ab, scal);
  k_pass<false><<<NN * NCH, 256, 0, stream>>>(feat, P1, ab, Apart, SWpart, out_attn);
  k_slot4<true, false><<<NN * MM, 256, 0, stream>>>(slots_init, Apart, SWpart, WvT, WqT, W1T, W2T,
                                                    out_g, out_b, b1, b2, q_g, q_b, Wk, kv_g, kv_b,
                                                    scal, slotbuf, P2, ab2, out, out_attn);
  k_pass<true><<<NN * NCH, 256, 0, stream>>>(feat, P2, ab2, Apart, SWpart, out_attn);
  k_slot4<false, true><<<NN * MM, 256, 0, stream>>>(slots_init, Apart, SWpart, WvT, WqT, W1T, W2T,
                                                    out_g, out_b, b1, b2, q_g, q_b, Wk, kv_g, kv_b,
                                                    scal, slotbuf, P2, ab2, out, out_attn);
}